// Round 2
// baseline (385.997 us; speedup 1.0000x reference)
//
#include <hip/hip_runtime.h>
#include <cstdint>
#include <cstddef>

// B=8 H=16 KVH=2 D=128 S=16 T=8192 HID=2048, G=8
// d_out = [out 262144][new_k 16777216][new_v 16777216] fp32

typedef __attribute__((ext_vector_type(8))) short bf16x8;
typedef __attribute__((ext_vector_type(4))) float f32x4;
typedef unsigned short u16;
typedef unsigned int u32;

#define MFMA16(a, b, c) __builtin_amdgcn_mfma_f32_16x16x32_bf16(a, b, c, 0, 0, 0)

static __device__ __forceinline__ u16 f2bf(float f) {
  u32 u = __float_as_uint(f);
  u += 0x7FFFu + ((u >> 16) & 1u);   // RNE
  return (u16)(u >> 16);
}
static __device__ __forceinline__ float bf2f(u16 u) {
  return __uint_as_float(((u32)u) << 16);
}
static __device__ __forceinline__ u32 pk2(float a, float b) {
  return (u32)f2bf(a) | ((u32)f2bf(b) << 16);
}

// ---------------------------------------------------------------------------
// x [8][2048][1][16] f32 -> Xt bf16 [j=b*16+s][c] (row-major, 2048 cols)
// ---------------------------------------------------------------------------
__global__ __launch_bounds__(256) void transpose_x(const float* __restrict__ x,
                                                   u16* __restrict__ Xt) {
  int id = blockIdx.x * 256 + threadIdx.x;           // 65536 total
  int b = id >> 13, c = (id >> 2) & 2047, s4 = id & 3;
  float4 v = *(const float4*)(x + ((size_t)(b * 2048 + c)) * 16 + s4 * 4);
  size_t base = (size_t)(b * 16 + s4 * 4) * 2048 + c;
  Xt[base]        = f2bf(v.x);
  Xt[base + 2048] = f2bf(v.y);
  Xt[base + 4096] = f2bf(v.z);
  Xt[base + 6144] = f2bf(v.w);
}

// ---------------------------------------------------------------------------
// GEMM: D[m][j] = sum_c W[m][c] * Bt[j][c],  K=2048, N=128, M-tile=16.
// 512 threads: in-block K-split (half 0: c<1024, half 1: c>=1024) + LDS reduce.
// MODE 0: W = concat(wq,wk,wv); store TRANSPOSED qkvT[j*2560 + m] (float4).
// MODE 1: W = wo; store out[(j>>4)*32768 + m*16 + (j&15)].
// grid.x = M/16; block 512.
// ---------------------------------------------------------------------------
template <int MODE>
__global__ __launch_bounds__(512) void gemm16(const float* __restrict__ w0,
                                              const float* __restrict__ w1,
                                              const float* __restrict__ w2,
                                              const u16* __restrict__ Bt,
                                              float* __restrict__ outp) {
  __shared__ __align__(16) u16 sW[2][16 * 256];   // 16 KB
  __shared__ __align__(16) float sRed[2048];      // 8 KB
  const int t512 = threadIdx.x;
  const int half = t512 >> 8;          // K-split id
  const int tid = t512 & 255;
  const int lane = tid & 63, w = tid >> 6;
  const int q = lane >> 4, n = lane & 15;
  const int m0 = blockIdx.x * 16;
  const float* wbase;
  if (MODE == 0) {
    if (m0 < 2048)      wbase = w0 + (size_t)m0 * 2048;
    else if (m0 < 2304) wbase = w1 + (size_t)(m0 - 2048) * 2048;
    else                wbase = w2 + (size_t)(m0 - 2304) * 2048;
  } else {
    wbase = w0 + (size_t)m0 * 2048;
  }
  const int kbase = half * 1024;
  f32x4 acc0 = {0.f, 0.f, 0.f, 0.f}, acc1 = acc0;

  for (int c0 = kbase; c0 < kbase + 1024; c0 += 256) {
    {  // stage W tile 16x256 -> bf16, granule-rotated
      int m = tid >> 4, s16 = tid & 15;
      const float* src = wbase + (size_t)m * 2048 + c0 + s16 * 16;
      float4 a = *(const float4*)(src);
      float4 b = *(const float4*)(src + 4);
      float4 c = *(const float4*)(src + 8);
      float4 d = *(const float4*)(src + 12);
      uint4 u0 = {pk2(a.x, a.y), pk2(a.z, a.w), pk2(b.x, b.y), pk2(b.z, b.w)};
      uint4 u1 = {pk2(c.x, c.y), pk2(c.z, c.w), pk2(d.x, d.y), pk2(d.z, d.w)};
      int G0 = 2 * s16;
      *(uint4*)&sW[half][m * 256 + ((G0 + m) & 31) * 8]     = u0;
      *(uint4*)&sW[half][m * 256 + ((G0 + 1 + m) & 31) * 8] = u1;
    }
    __syncthreads();
    // B-fragments straight from global (Bt is small, L2-resident)
    bf16x8 bfr[2][8];
#pragma unroll
    for (int e = 0; e < 2; ++e) {
      int j = 32 * w + 16 * e + n;
      const u16* bp = Bt + (size_t)j * 2048 + c0 + q * 8;
#pragma unroll
      for (int ks = 0; ks < 8; ++ks) bfr[e][ks] = *(const bf16x8*)(bp + ks * 32);
    }
#pragma unroll
    for (int ks = 0; ks < 8; ++ks) {
      bf16x8 af = *(const bf16x8*)&sW[half][n * 256 + (((4 * ks + q) + n) & 31) * 8];
      acc0 = MFMA16(af, bfr[0][ks], acc0);
      acc1 = MFMA16(af, bfr[1][ks], acc1);
    }
    __syncthreads();
  }
  // combine the two K-halves
  if (half == 1) {
    *(f32x4*)&sRed[tid * 8]     = acc0;
    *(f32x4*)&sRed[tid * 8 + 4] = acc1;
  }
  __syncthreads();
  if (half == 0) {
    acc0 += *(const f32x4*)&sRed[tid * 8];
    acc1 += *(const f32x4*)&sRed[tid * 8 + 4];
#pragma unroll
    for (int e = 0; e < 2; ++e) {
      f32x4 a = e ? acc1 : acc0;
      int j = 32 * w + 16 * e + n;
      if (MODE == 0) {
        // transposed store: 4 consecutive m at fixed j -> one float4
        *(f32x4*)&outp[(size_t)j * 2560 + m0 + 4 * q] = a;
      } else {
#pragma unroll
        for (int reg = 0; reg < 4; ++reg) {
          int m = m0 + 4 * q + reg;
          outp[(size_t)(j >> 4) * 32768 + m * 16 + (j & 15)] = a[reg];
        }
      }
    }
  }
}

// ---------------------------------------------------------------------------
// RMSNorm + rotary. One wave per row; 2560 waves. qkvT layout: [j=b*16+s][2560].
//  0..2047   : q -> Qa bf16 [b][h][s][d], pre-scaled by 1/sqrt(D)
//  2048..2303: k -> knew f32; 2304..2559: v -> vnew f32 (copy)
// ---------------------------------------------------------------------------
__global__ __launch_bounds__(256) void norm_rot(
    const float* __restrict__ qkv, const float* __restrict__ cosb,
    const float* __restrict__ sinb, const float* __restrict__ qw,
    const float* __restrict__ kw,
    u16* __restrict__ Qa, float* __restrict__ knew, float* __restrict__ vnew) {
  const int wid = blockIdx.x * 4 + (threadIdx.x >> 6);
  const int lane = threadIdx.x & 63;
  const float SCALE = 0.08838834764831845f;  // 1/sqrt(128)
  if (wid < 2048) {
    int b = wid >> 8, h = (wid >> 4) & 15, s = wid & 15;
    int j = b * 16 + s;
    const float* row = qkv + (size_t)j * 2560 + h * 128;
    float v1 = row[lane];
    float v2 = row[lane + 64];
    float ss = v1 * v1 + v2 * v2;
#pragma unroll
    for (int o = 32; o > 0; o >>= 1) ss += __shfl_xor(ss, o, 64);
    float rr = rsqrtf(ss * (1.0f / 128.0f) + 1e-6f);
    float n1 = v1 * rr * qw[lane];
    float n2 = v2 * rr * qw[lane + 64];
    float c = cosb[s * 64 + lane], sn = sinb[s * 64 + lane];
    u16* dst = Qa + (size_t)((b * 16 + h) * 16 + s) * 128;
    dst[lane]      = f2bf((n1 * c - n2 * sn) * SCALE);
    dst[lane + 64] = f2bf((n2 * c + n1 * sn) * SCALE);
  } else if (wid < 2304) {
    int idx = wid - 2048;
    int b = idx >> 5, kvh = (idx >> 4) & 1, s = idx & 15;
    int j = b * 16 + s;
    const float* row = qkv + (size_t)j * 2560 + 2048 + kvh * 128;
    float v1 = row[lane];
    float v2 = row[lane + 64];
    float ss = v1 * v1 + v2 * v2;
#pragma unroll
    for (int o = 32; o > 0; o >>= 1) ss += __shfl_xor(ss, o, 64);
    float rr = rsqrtf(ss * (1.0f / 128.0f) + 1e-6f);
    float n1 = v1 * rr * kw[lane];
    float n2 = v2 * rr * kw[lane + 64];
    float c = cosb[s * 64 + lane], sn = sinb[s * 64 + lane];
    float* dst = knew + (size_t)((b * 2 + kvh) * 16 + s) * 128;
    dst[lane]      = n1 * c - n2 * sn;
    dst[lane + 64] = n2 * c + n1 * sn;
  } else {
    int idx = wid - 2304;
    int b = idx >> 5, kvh = (idx >> 4) & 1, s = idx & 15;
    int j = b * 16 + s;
    const float* row = qkv + (size_t)j * 2560 + 2304 + kvh * 128;
    float* dst = vnew + (size_t)((b * 2 + kvh) * 16 + s) * 128;
    dst[lane]      = row[lane];
    dst[lane + 64] = row[lane + 64];
  }
}

// ---------------------------------------------------------------------------
// Flash attention, MFMA. grid 512 = bk(16) x chunk(32 of 256 keys); block 256.
// Per block: 128 q-rows x 256 keys (4 tiles of 64). S^T = K·Q^T, V transposed
// via MFMA-by-identity. P never touches LDS: the PV A-fragment is assembled
// in-register via intra-wave shuffles from the S^T C-layout.
// LDS 48 KB (K 16 | V 16 | Vt 16) -> 3 blocks/CU (12 waves, was 8).
// Q frags direct from global; 2 barriers/tile; setprio(1) around MFMA.
// ---------------------------------------------------------------------------
__global__ __launch_bounds__(256, 3) void attn(
    const u16* __restrict__ Qa, const float* __restrict__ kcache,
    const float* __restrict__ vcache, const float* __restrict__ knew,
    const float* __restrict__ vnew, const int* __restrict__ posp,
    const float* __restrict__ mask, float* __restrict__ outk,
    float* __restrict__ outv, u16* __restrict__ Opart,
    float* __restrict__ Mpart, float* __restrict__ Lpart) {
  __shared__ __align__(16) u16 lds[24576];  // 48 KB: K[0..8192) V[8192..16384) Vt[16384..24576)

  const int tid = threadIdx.x, lane = tid & 63, w = tid >> 6;
  const int q = lane >> 4, n = lane & 15;
  const int bid = blockIdx.x;
  const int bk = bid >> 5, chunk = bid & 31;
  const int b = bk >> 1, kvh = bk & 1;
  const int pos = *posp;
  const int stl = tid >> 4;   // staging row base
  const int g = tid & 15;     // staging granule

  // ---- Q fragments direct from global (written by norm_rot, L2-resident)
  bf16x8 qf[2][4];
#pragma unroll
  for (int e = 0; e < 2; ++e) {
    int r = 32 * w + 16 * e + n;
    int h = kvh * 8 + (r >> 4), s = r & 15;
    const u16* qrow = Qa + (size_t)((b * 16 + h) * 16 + s) * 128;
#pragma unroll
    for (int ks = 0; ks < 4; ++ks)
      qf[e][ks] = *(const bf16x8*)(qrow + (4 * ks + q) * 8);
  }

  // identity B-frags for MFMA transpose (one-hot bf16 1.0)
  bf16x8 idE = {0, 0, 0, 0, 0, 0, 0, 0}, idO = idE;
  {
    const short one = (short)0x3F80;
    int tq = n >> 3, te = n & 7;
#pragma unroll
    for (int e = 0; e < 8; ++e) {
      if (q == tq && e == te) idE[e] = one;
      if (q == tq + 2 && e == te) idO[e] = one;
    }
  }

  float m_old[2] = {-INFINITY, -INFINITY}, l_old[2] = {0.f, 0.f};
  f32x4 oacc[2][8];
#pragma unroll
  for (int e = 0; e < 2; ++e)
#pragma unroll
    for (int nt = 0; nt < 8; ++nt) oacc[e][nt] = (f32x4){0.f, 0.f, 0.f, 0.f};

  for (int tile = 0; tile < 4; ++tile) {
    const int t0 = chunk * 256 + tile * 64;
    // ---- stage K,V: global load + cache-copy store + bf16 pack to LDS
#pragma unroll
    for (int u = 0; u < 8; ++u) {
      int isV = u >> 2;
      int tl = (stl + 16 * u) & 63;
      int tg = t0 + tl;
      const float* src;
      if (!isV)
        src = (tg >= pos && tg < pos + 16)
                  ? (knew + (size_t)(bk * 16 + (tg - pos)) * 128)
                  : (kcache + ((size_t)bk * 8192 + tg) * 128);
      else
        src = (tg >= pos && tg < pos + 16)
                  ? (vnew + (size_t)(bk * 16 + (tg - pos)) * 128)
                  : (vcache + ((size_t)bk * 8192 + tg) * 128);
      float* dst = (isV ? outv : outk) + ((size_t)bk * 8192 + tg) * 128 + g * 8;
      float4 a = *(const float4*)(src + g * 8);
      float4 b2 = *(const float4*)(src + g * 8 + 4);
      *(float4*)dst = a;
      *(float4*)(dst + 4) = b2;
      uint4 uu = {pk2(a.x, a.y), pk2(a.z, a.w), pk2(b2.x, b2.y), pk2(b2.z, b2.w)};
      *(uint4*)&lds[isV * 8192 + tl * 128 + ((g + tl) & 15) * 8] = uu;
    }
    __syncthreads();  // A: LDS K/V ready; prev-tile PV (Vt reads) all done

    // mask values for this tile (s-row = n); overlaps QK^T below
    float4 mv4[4];
#pragma unroll
    for (int mt = 0; mt < 4; ++mt)
      mv4[mt] = *(const float4*)(mask + (size_t)n * 8192 + t0 + 16 * mt + 4 * q);

    // ---- S^T = K·Q^T
    f32x4 sacc[4][2];
#pragma unroll
    for (int mt = 0; mt < 4; ++mt) {
      sacc[mt][0] = (f32x4){0.f, 0.f, 0.f, 0.f};
      sacc[mt][1] = sacc[mt][0];
    }
    __builtin_amdgcn_s_setprio(1);
#pragma unroll
    for (int ks = 0; ks < 4; ++ks) {
#pragma unroll
      for (int mt = 0; mt < 4; ++mt) {
        int trow = 16 * mt + n;
        bf16x8 kf = *(const bf16x8*)&lds[trow * 128 + (((4 * ks + q) + trow) & 15) * 8];
        sacc[mt][0] = MFMA16(kf, qf[0][ks], sacc[mt][0]);
        sacc[mt][1] = MFMA16(kf, qf[1][ks], sacc[mt][1]);
      }
    }
    __builtin_amdgcn_s_setprio(0);

    // ---- V transpose via MFMA identity: Vt[d][t], wave w does d in [32w,32w+32)
#pragma unroll
    for (int mtv = 0; mtv < 4; ++mtv) {
      int trow = 16 * mtv + n;
      bf16x8 vfr = *(const bf16x8*)&lds[8192 + trow * 128 + (((4 * w + q) + trow) & 15) * 8];
      f32x4 z = {0.f, 0.f, 0.f, 0.f};
      f32x4 d0 = MFMA16(vfr, idE, z);
      f32x4 d1 = MFMA16(vfr, idO, z);
      int G = 2 * mtv + (q >> 1), off = 4 * (q & 1);
      int dp0 = 32 * w + n, dp1 = dp0 + 16;
      uint2 u0 = {pk2(d0[0], d0[1]), pk2(d0[2], d0[3])};
      uint2 u1 = {pk2(d1[0], d1[1]), pk2(d1[2], d1[3])};
      *(uint2*)&lds[16384 + dp0 * 64 + ((G + dp0) & 7) * 8 + off] = u0;
      *(uint2*)&lds[16384 + dp1 * 64 + ((G + dp1) & 7) * 8 + off] = u1;
    }

    // ---- online softmax (in-register) + P A-frags via intra-wave shuffles.
    // Lane (q,n) holds P[r=32w+16e+n][t=16mt+4q+rg]; the PV A-frag needs
    // t = 32ks+8q+j at the same n. Word i of frag ks comes from lane
    // q_h = 2(q&1)+(i>>1) (same n), array U[2ks+(q>>1)][i&1].
    float al[2];
    bf16x8 Pf[2][2];
#pragma unroll
    for (int e = 0; e < 2; ++e) {
      float sv[4][4];
      float mx = -INFINITY;
#pragma unroll
      for (int mt = 0; mt < 4; ++mt)
#pragma unroll
        for (int rg = 0; rg < 4; ++rg) {
          float v = sacc[mt][e][rg] + mv4[mt][rg];
          sv[mt][rg] = v;
          mx = fmaxf(mx, v);
        }
      mx = fmaxf(mx, __shfl_xor(mx, 16));
      mx = fmaxf(mx, __shfl_xor(mx, 32));
      float mn = fmaxf(m_old[e], mx);
      al[e] = __expf(m_old[e] - mn);
      float ts = 0.f;
      u32 U[4][2];
#pragma unroll
      for (int mt = 0; mt < 4; ++mt) {
        float p0 = __expf(sv[mt][0] - mn), p1 = __expf(sv[mt][1] - mn);
        float p2 = __expf(sv[mt][2] - mn), p3 = __expf(sv[mt][3] - mn);
        ts += (p0 + p1) + (p2 + p3);
        U[mt][0] = pk2(p0, p1);
        U[mt][1] = pk2(p2, p3);
      }
      ts += __shfl_xor(ts, 16);
      ts += __shfl_xor(ts, 32);
      l_old[e] = l_old[e] * al[e] + ts;
      m_old[e] = mn;
      const int srcbase = n + ((q & 1) << 5);
#pragma unroll
      for (int ks = 0; ks < 2; ++ks) {
        u32 pw[4];
#pragma unroll
        for (int i = 0; i < 4; ++i) {
          int src = srcbase + ((i >> 1) << 4);
          u32 lo = (u32)__shfl((int)U[2 * ks][i & 1], src, 64);
          u32 hi = (u32)__shfl((int)U[2 * ks + 1][i & 1], src, 64);
          pw[i] = (q >> 1) ? hi : lo;
        }
        uint4 pv = {pw[0], pw[1], pw[2], pw[3]};
        Pf[e][ks] = __builtin_bit_cast(bf16x8, pv);
      }
    }
    __syncthreads();  // B: Vt ready for all waves

    // ---- O rescale (alpha via in-wave shuffle) + PV
#pragma unroll
    for (int e = 0; e < 2; ++e) {
      float an[4];
#pragma unroll
      for (int rg = 0; rg < 4; ++rg) an[rg] = __shfl(al[e], 4 * q + rg, 64);
#pragma unroll
      for (int nt = 0; nt < 8; ++nt)
#pragma unroll
        for (int rg = 0; rg < 4; ++rg) oacc[e][nt][rg] *= an[rg];
    }
    __builtin_amdgcn_s_setprio(1);
#pragma unroll
    for (int nt = 0; nt < 8; ++nt) {
      int d = 16 * nt + n;
#pragma unroll
      for (int ks = 0; ks < 2; ++ks) {
        bf16x8 vf = *(const bf16x8*)&lds[16384 + d * 64 + (((4 * ks + q) + d) & 7) * 8];
        oacc[0][nt] = MFMA16(Pf[0][ks], vf, oacc[0][nt]);
        oacc[1][nt] = MFMA16(Pf[1][ks], vf, oacc[1][nt]);
      }
    }
    __builtin_amdgcn_s_setprio(0);
    // no barrier here: next stage writes K/V regions only; all K/V reads
    // happened before barrier B. Vt rewrite happens after next barrier A.
  }

  // ---- epilogue: O^T bf16 -> lds[0..16384) (rotated) -> coalesced global
#pragma unroll
  for (int e = 0; e < 2; ++e)
#pragma unroll
    for (int nt = 0; nt < 8; ++nt) {
      int d = 16 * nt + n;
      int r0 = 32 * w + 16 * e + 4 * q;
      int G = r0 >> 3, off = 4 * (q & 1);
      uint2 u = {pk2(oacc[e][nt][0], oacc[e][nt][1]),
                 pk2(oacc[e][nt][2], oacc[e][nt][3])};
      *(uint2*)&lds[d * 128 + ((G + d) & 15) * 8 + off] = u;
    }
  if (q == 0) {
#pragma unroll
    for (int e = 0; e < 2; ++e) {
      int r = 32 * w + 16 * e + n;
      Mpart[(size_t)bid * 128 + r] = m_old[e];
      Lpart[(size_t)bid * 128 + r] = l_old[e];
    }
  }
  __syncthreads();
  for (int i = tid; i < 2048; i += 256) {
    int d2 = i >> 4, g2 = i & 15;
    uint4 v = *(const uint4*)&lds[d2 * 128 + ((g2 + d2) & 15) * 8];
    *(uint4*)(Opart + (size_t)bid * 16384 + d2 * 128 + g2 * 8) = v;
  }
}

// ---------------------------------------------------------------------------
// Combine 32 chunk partials -> A2t bf16 [j=b*16+s][c=h*128+d]
// grid (16 bk, 16 dgrp) x 256; 4 interleaved accumulators for load ILP.
// ---------------------------------------------------------------------------
__global__ __launch_bounds__(256) void combine(const u16* __restrict__ Opart,
                                               const float* __restrict__ Mp,
                                               const float* __restrict__ Lp,
                                               u16* __restrict__ A2t) {
  __shared__ float wgt[32 * 128];  // 16 KB
  const int tid = threadIdx.x;
  const int bk = blockIdx.x, dgrp = blockIdx.y;
  if (tid < 128) {
    int r = tid;
    float mc[32], M = -INFINITY;
#pragma unroll
    for (int c = 0; c < 32; ++c) {
      mc[c] = Mp[(size_t)(bk * 32 + c) * 128 + r];
      M = fmaxf(M, mc[c]);
    }
    float L = 0.f, wv[32];
#pragma unroll
    for (int c = 0; c < 32; ++c) {
      wv[c] = __expf(mc[c] - M);
      L += wv[c] * Lp[(size_t)(bk * 32 + c) * 128 + r];
    }
    float inv = 1.0f / L;
#pragma unroll
    for (int c = 0; c < 32; ++c) wgt[c * 128 + r] = wv[c] * inv;
  }
  __syncthreads();
  int r = tid & 127, dd = tid >> 7;
  int b = bk >> 1, kvh = bk & 1;
  int h = kvh * 8 + (r >> 4), s = r & 15;
  size_t arow = (size_t)(b * 16 + s) * 2048 + h * 128;
  float o[4] = {0.f, 0.f, 0.f, 0.f};
#pragma unroll
  for (int c = 0; c < 32; ++c) {
    float wv = wgt[c * 128 + r];
    size_t base = ((size_t)(bk * 32 + c) * 128) * 128 + r;
#pragma unroll
    for (int di = 0; di < 4; ++di) {
      int d = dgrp * 8 + dd + 2 * di;
      o[di] += wv * bf2f(Opart[base + (size_t)d * 128]);
    }
  }
#pragma unroll
  for (int di = 0; di < 4; ++di) {
    int d = dgrp * 8 + dd + 2 * di;
    A2t[arow + d] = f2bf(o[di]);
  }
}

// ---------------------------------------------------------------------------
extern "C" void kernel_launch(void* const* d_in, const int* in_sizes, int n_in,
                              void* d_out, int out_size, void* d_ws, size_t ws_size,
                              hipStream_t stream) {
  const float* x    = (const float*)d_in[0];
  const float* cosb = (const float*)d_in[1];
  const float* sinb = (const float*)d_in[2];
  const float* kc   = (const float*)d_in[3];
  const float* vc   = (const float*)d_in[4];
  const int*   posp = (const int*)d_in[5];
  const float* mask = (const float*)d_in[6];
  const float* wq   = (const float*)d_in[7];
  const float* wk   = (const float*)d_in[8];
  const float* wv   = (const float*)d_in[9];
  const float* wo   = (const float*)d_in[10];
  const float* qw   = (const float*)d_in[11];
  const float* kw   = (const float*)d_in[12];

  float* out  = (float*)d_out;
  float* outk = out + 262144;
  float* outv = outk + 16777216;

  float* ws      = (float*)d_ws;
  float* ws_qkv  = ws;                        // 327680 f32, qkvT [128 j][2560 m]
  float* ws_knew = ws + 327680;               // 32768
  float* ws_vnew = ws + 360448;               // 32768
  u16*   ws_Qa   = (u16*)(ws + 393216);       // 262144 u16
  u16*   ws_Xt   = (u16*)(ws + 524288);       // 262144 u16
  u16*   ws_A2t  = (u16*)(ws + 655360);       // 262144 u16
  float* ws_M    = ws + 786432;               // 65536
  float* ws_L    = ws + 851968;               // 65536
  u16*   ws_O    = (u16*)(ws + 917504);       // 8388608 u16 (bf16 partials)
  // total = 5,111,808 floats = 20.45 MB

  transpose_x<<<256, 256, 0, stream>>>(x, ws_Xt);
  gemm16<0><<<160, 512, 0, stream>>>(wq, wk, wv, ws_Xt, ws_qkv);
  norm_rot<<<640, 256, 0, stream>>>(ws_qkv, cosb, sinb, qw, kw,
                                    ws_Qa, ws_knew, ws_vnew);
  attn<<<512, 256, 0, stream>>>(ws_Qa, kc, vc, ws_knew, ws_vnew, posp, mask,
                                outk, outv, ws_O, ws_M, ws_L);
  combine<<<dim3(16, 16), 256, 0, stream>>>(ws_O, ws_M, ws_L, ws_A2t);
  gemm16<1><<<128, 512, 0, stream>>>(wo, wo, wo, ws_A2t, out);
}

// Round 3
// 332.399 us; speedup vs baseline: 1.1612x; 1.1612x over previous
//
#include <hip/hip_runtime.h>
#include <cstdint>
#include <cstddef>

// B=8 H=16 KVH=2 D=128 S=16 T=8192 HID=2048, G=8
// d_out = [out 262144][new_k 16777216][new_v 16777216] fp32

typedef __attribute__((ext_vector_type(8))) short bf16x8;
typedef __attribute__((ext_vector_type(4))) float f32x4;
typedef unsigned short u16;
typedef unsigned int u32;

#define MFMA16(a, b, c) __builtin_amdgcn_mfma_f32_16x16x32_bf16(a, b, c, 0, 0, 0)

static __device__ __forceinline__ u16 f2bf(float f) {
  u32 u = __float_as_uint(f);
  u += 0x7FFFu + ((u >> 16) & 1u);   // RNE
  return (u16)(u >> 16);
}
static __device__ __forceinline__ float bf2f(u16 u) {
  return __uint_as_float(((u32)u) << 16);
}
static __device__ __forceinline__ u32 pk2(float a, float b) {
  return (u32)f2bf(a) | ((u32)f2bf(b) << 16);
}

// ---------------------------------------------------------------------------
// x [8][2048][1][16] f32 -> Xt bf16 [j=b*16+s][c] (row-major, 2048 cols)
// ---------------------------------------------------------------------------
__global__ __launch_bounds__(256) void transpose_x(const float* __restrict__ x,
                                                   u16* __restrict__ Xt) {
  int id = blockIdx.x * 256 + threadIdx.x;           // 65536 total
  int b = id >> 13, c = (id >> 2) & 2047, s4 = id & 3;
  float4 v = *(const float4*)(x + ((size_t)(b * 2048 + c)) * 16 + s4 * 4);
  size_t base = (size_t)(b * 16 + s4 * 4) * 2048 + c;
  Xt[base]        = f2bf(v.x);
  Xt[base + 2048] = f2bf(v.y);
  Xt[base + 4096] = f2bf(v.z);
  Xt[base + 6144] = f2bf(v.w);
}

// ---------------------------------------------------------------------------
// GEMM, grid-level K-split: D_p[m][j] = sum_{c in slice p} W[m][c]*Bt[j][c].
// K=2048 -> 8 slices of 256. grid (M/16, 8) x 256 threads. One staging
// iteration + 16 MFMAs per block -> short serial chain, 4-5 blocks/CU.
// MODE 0: W = concat(wq,wk,wv); partial store qkvp[kp][j][2560] (float4).
// MODE 1: W = wo; partial store outp[kp*262144 + b*32768 + m*16 + s].
// ---------------------------------------------------------------------------
template <int MODE>
__global__ __launch_bounds__(256) void gemm16(const float* __restrict__ w0,
                                              const float* __restrict__ w1,
                                              const float* __restrict__ w2,
                                              const u16* __restrict__ Bt,
                                              float* __restrict__ outp) {
  __shared__ __align__(16) u16 sW[16 * 256];  // 8 KB, granule-rotated
  const int tid = threadIdx.x, lane = tid & 63, w = tid >> 6;
  const int q = lane >> 4, n = lane & 15;
  const int m0 = blockIdx.x * 16;
  const int kp = blockIdx.y;
  const int kbase = kp * 256;
  const float* wbase;
  if (MODE == 0) {
    if (m0 < 2048)      wbase = w0 + (size_t)m0 * 2048;
    else if (m0 < 2304) wbase = w1 + (size_t)(m0 - 2048) * 2048;
    else                wbase = w2 + (size_t)(m0 - 2304) * 2048;
  } else {
    wbase = w0 + (size_t)m0 * 2048;
  }
  {  // stage W tile 16x256 -> bf16, granule-rotated
    int m = tid >> 4, s16 = tid & 15;
    const float* src = wbase + (size_t)m * 2048 + kbase + s16 * 16;
    float4 a = *(const float4*)(src);
    float4 b = *(const float4*)(src + 4);
    float4 c = *(const float4*)(src + 8);
    float4 d = *(const float4*)(src + 12);
    uint4 u0 = {pk2(a.x, a.y), pk2(a.z, a.w), pk2(b.x, b.y), pk2(b.z, b.w)};
    uint4 u1 = {pk2(c.x, c.y), pk2(c.z, c.w), pk2(d.x, d.y), pk2(d.z, d.w)};
    int G0 = 2 * s16;
    *(uint4*)&sW[m * 256 + ((G0 + m) & 31) * 8]     = u0;
    *(uint4*)&sW[m * 256 + ((G0 + 1 + m) & 31) * 8] = u1;
  }
  // B-fragments straight from global (Bt is small, L2-resident)
  bf16x8 bfr[2][8];
#pragma unroll
  for (int e = 0; e < 2; ++e) {
    int j = 32 * w + 16 * e + n;
    const u16* bp = Bt + (size_t)j * 2048 + kbase + q * 8;
#pragma unroll
    for (int ks = 0; ks < 8; ++ks) bfr[e][ks] = *(const bf16x8*)(bp + ks * 32);
  }
  __syncthreads();
  f32x4 acc0 = {0.f, 0.f, 0.f, 0.f}, acc1 = acc0;
#pragma unroll
  for (int ks = 0; ks < 8; ++ks) {
    bf16x8 af = *(const bf16x8*)&sW[n * 256 + (((4 * ks + q) + n) & 31) * 8];
    acc0 = MFMA16(af, bfr[0][ks], acc0);
    acc1 = MFMA16(af, bfr[1][ks], acc1);
  }
#pragma unroll
  for (int e = 0; e < 2; ++e) {
    f32x4 a = e ? acc1 : acc0;
    int j = 32 * w + 16 * e + n;
    if (MODE == 0) {
      // transposed partial: 4 consecutive m at fixed j -> one float4
      *(f32x4*)&outp[(size_t)kp * 327680 + (size_t)j * 2560 + m0 + 4 * q] = a;
    } else {
#pragma unroll
      for (int reg = 0; reg < 4; ++reg) {
        int m = m0 + 4 * q + reg;
        outp[(size_t)kp * 262144 + (size_t)(j >> 4) * 32768 + m * 16 + (j & 15)] =
            a[reg];
      }
    }
  }
}

// ---------------------------------------------------------------------------
// Sum 8 K-partials of the wo GEMM -> out (262144 f32).
// ---------------------------------------------------------------------------
__global__ __launch_bounds__(256) void reduce_out(const float* __restrict__ part,
                                                  float* __restrict__ out) {
  int i = blockIdx.x * 256 + threadIdx.x;  // 65536 float4s
  f32x4 acc = {0.f, 0.f, 0.f, 0.f};
#pragma unroll
  for (int p = 0; p < 8; ++p)
    acc += *(const f32x4*)(part + (size_t)p * 262144 + (size_t)i * 4);
  *(f32x4*)(out + (size_t)i * 4) = acc;
}

// ---------------------------------------------------------------------------
// RMSNorm + rotary, fused 8-partial reduction of the qkv GEMM.
// One wave per row; 2560 waves. qkvp layout: [p][j=b*16+s][2560].
//  0..2047   : q -> Qa bf16 [b][h][s][d], pre-scaled by 1/sqrt(D)
//  2048..2303: k -> knew f32; 2304..2559: v -> vnew f32 (copy)
// ---------------------------------------------------------------------------
__global__ __launch_bounds__(256) void norm_rot(
    const float* __restrict__ qkvp, const float* __restrict__ cosb,
    const float* __restrict__ sinb, const float* __restrict__ qw,
    const float* __restrict__ kw,
    u16* __restrict__ Qa, float* __restrict__ knew, float* __restrict__ vnew) {
  const int wid = blockIdx.x * 4 + (threadIdx.x >> 6);
  const int lane = threadIdx.x & 63;
  const float SCALE = 0.08838834764831845f;  // 1/sqrt(128)
  if (wid < 2048) {
    int b = wid >> 8, h = (wid >> 4) & 15, s = wid & 15;
    int j = b * 16 + s;
    const float* row = qkvp + (size_t)j * 2560 + h * 128;
    float v1 = 0.f, v2 = 0.f;
#pragma unroll
    for (int p = 0; p < 8; ++p) {
      v1 += row[(size_t)p * 327680 + lane];
      v2 += row[(size_t)p * 327680 + lane + 64];
    }
    float ss = v1 * v1 + v2 * v2;
#pragma unroll
    for (int o = 32; o > 0; o >>= 1) ss += __shfl_xor(ss, o, 64);
    float rr = rsqrtf(ss * (1.0f / 128.0f) + 1e-6f);
    float n1 = v1 * rr * qw[lane];
    float n2 = v2 * rr * qw[lane + 64];
    float c = cosb[s * 64 + lane], sn = sinb[s * 64 + lane];
    u16* dst = Qa + (size_t)((b * 16 + h) * 16 + s) * 128;
    dst[lane]      = f2bf((n1 * c - n2 * sn) * SCALE);
    dst[lane + 64] = f2bf((n2 * c + n1 * sn) * SCALE);
  } else if (wid < 2304) {
    int idx = wid - 2048;
    int b = idx >> 5, kvh = (idx >> 4) & 1, s = idx & 15;
    int j = b * 16 + s;
    const float* row = qkvp + (size_t)j * 2560 + 2048 + kvh * 128;
    float v1 = 0.f, v2 = 0.f;
#pragma unroll
    for (int p = 0; p < 8; ++p) {
      v1 += row[(size_t)p * 327680 + lane];
      v2 += row[(size_t)p * 327680 + lane + 64];
    }
    float ss = v1 * v1 + v2 * v2;
#pragma unroll
    for (int o = 32; o > 0; o >>= 1) ss += __shfl_xor(ss, o, 64);
    float rr = rsqrtf(ss * (1.0f / 128.0f) + 1e-6f);
    float n1 = v1 * rr * kw[lane];
    float n2 = v2 * rr * kw[lane + 64];
    float c = cosb[s * 64 + lane], sn = sinb[s * 64 + lane];
    float* dst = knew + (size_t)((b * 2 + kvh) * 16 + s) * 128;
    dst[lane]      = n1 * c - n2 * sn;
    dst[lane + 64] = n2 * c + n1 * sn;
  } else {
    int idx = wid - 2304;
    int b = idx >> 5, kvh = (idx >> 4) & 1, s = idx & 15;
    int j = b * 16 + s;
    const float* row = qkvp + (size_t)j * 2560 + 2304 + kvh * 128;
    float v1 = 0.f, v2 = 0.f;
#pragma unroll
    for (int p = 0; p < 8; ++p) {
      v1 += row[(size_t)p * 327680 + lane];
      v2 += row[(size_t)p * 327680 + lane + 64];
    }
    float* dst = vnew + (size_t)((b * 2 + kvh) * 16 + s) * 128;
    dst[lane]      = v1;
    dst[lane + 64] = v2;
  }
}

// ---------------------------------------------------------------------------
// Flash attention, MFMA. grid 512 = bk(16) x chunk(32 of 256 keys); block 256.
// Per block: 128 q-rows x 256 keys (4 tiles of 64). S^T = K·Q^T (no transposes),
// V transposed via MFMA-by-identity, P via contiguous ushort4 from C-layout.
// LDS: sQ 32KB (Q then K|V natural), sP 16KB, sVt 16KB = 64KB exactly.
// (Round-0 proven version: 92 us, VGPR 104, no spills.)
// ---------------------------------------------------------------------------
__global__ __launch_bounds__(256, 2) void attn(
    const u16* __restrict__ Qa, const float* __restrict__ kcache,
    const float* __restrict__ vcache, const float* __restrict__ knew,
    const float* __restrict__ vnew, const int* __restrict__ posp,
    const float* __restrict__ mask, float* __restrict__ outk,
    float* __restrict__ outv, u16* __restrict__ Opart,
    float* __restrict__ Mpart, float* __restrict__ Lpart) {
  __shared__ __align__(16) u16 sQ[16384];  // 32 KB: Q[128][128]; later K|V (8192 each)
  __shared__ __align__(16) u16 sP[8192];   // P[r(128)][t(64)] granule-rotated
  __shared__ __align__(16) u16 sVt[8192];  // Vt[d(128)][t(64)] granule-rotated

  const int tid = threadIdx.x, lane = tid & 63, w = tid >> 6;
  const int q = lane >> 4, n = lane & 15;
  const int bid = blockIdx.x;
  const int bk = bid >> 5, chunk = bid & 31;
  const int b = bk >> 1, kvh = bk & 1;
  const int pos = *posp;

  // ---- stage Q (bf16 global -> LDS, granule-rotated), preload B-frags
  for (int i = tid; i < 2048; i += 256) {
    int r = i >> 4, g = i & 15;
    int h = kvh * 8 + (r >> 4), s = r & 15;
    uint4 v = *(const uint4*)(Qa + (size_t)((b * 16 + h) * 16 + s) * 128 + g * 8);
    *(uint4*)&sQ[r * 128 + ((g + r) & 15) * 8] = v;
  }
  __syncthreads();
  bf16x8 qf[2][4];
#pragma unroll
  for (int e = 0; e < 2; ++e) {
    int r = 32 * w + 16 * e + n;
#pragma unroll
    for (int ks = 0; ks < 4; ++ks)
      qf[e][ks] = *(const bf16x8*)&sQ[r * 128 + (((4 * ks + q) + r) & 15) * 8];
  }
  __syncthreads();

  // identity B-frags for MFMA transpose (one-hot bf16 1.0)
  bf16x8 idE = {0, 0, 0, 0, 0, 0, 0, 0}, idO = idE;
  {
    const short one = (short)0x3F80;
    int tq = n >> 3, te = n & 7;
#pragma unroll
    for (int e = 0; e < 8; ++e) {
      if (q == tq && e == te) idE[e] = one;
      if (q == tq + 2 && e == te) idO[e] = one;
    }
  }

  float m_old[2] = {-INFINITY, -INFINITY}, l_old[2] = {0.f, 0.f};
  f32x4 oacc[2][8];
#pragma unroll
  for (int e = 0; e < 2; ++e)
#pragma unroll
    for (int nt = 0; nt < 8; ++nt) oacc[e][nt] = (f32x4){0.f, 0.f, 0.f, 0.f};

  for (int tile = 0; tile < 4; ++tile) {
    const int t0 = chunk * 256 + tile * 64;
    // ---- stage K,V natural bf16 (+ fused cache copy + new-row substitution)
    for (int i = tid; i < 2048; i += 256) {
      int isV = i >> 10;
      int tl = (i >> 4) & 63, g = i & 15;
      int tg = t0 + tl;
      const float* src;
      float* dst;
      if (!isV) {
        src = (tg >= pos && tg < pos + 16)
                  ? (knew + (size_t)(bk * 16 + (tg - pos)) * 128)
                  : (kcache + ((size_t)bk * 8192 + tg) * 128);
        dst = outk + ((size_t)bk * 8192 + tg) * 128;
      } else {
        src = (tg >= pos && tg < pos + 16)
                  ? (vnew + (size_t)(bk * 16 + (tg - pos)) * 128)
                  : (vcache + ((size_t)bk * 8192 + tg) * 128);
        dst = outv + ((size_t)bk * 8192 + tg) * 128;
      }
      float4 a = *(const float4*)(src + g * 8);
      float4 b2 = *(const float4*)(src + g * 8 + 4);
      *(float4*)(dst + g * 8) = a;
      *(float4*)(dst + g * 8 + 4) = b2;
      uint4 u = {pk2(a.x, a.y), pk2(a.z, a.w), pk2(b2.x, b2.y), pk2(b2.z, b2.w)};
      *(uint4*)&sQ[isV * 8192 + tl * 128 + ((g + tl) & 15) * 8] = u;
    }
    // mask values for this lane's S entries (s = n)
    float mv[4][4];
#pragma unroll
    for (int mt = 0; mt < 4; ++mt)
#pragma unroll
      for (int rg = 0; rg < 4; ++rg)
        mv[mt][rg] = mask[(size_t)n * 8192 + t0 + 16 * mt + 4 * q + rg];
    __syncthreads();  // A

    // ---- S^T = K·Q^T
    f32x4 sacc[4][2];
#pragma unroll
    for (int mt = 0; mt < 4; ++mt) {
      sacc[mt][0] = (f32x4){0.f, 0.f, 0.f, 0.f};
      sacc[mt][1] = sacc[mt][0];
    }
#pragma unroll
    for (int ks = 0; ks < 4; ++ks) {
#pragma unroll
      for (int mt = 0; mt < 4; ++mt) {
        int trow = 16 * mt + n;
        bf16x8 kf = *(const bf16x8*)&sQ[trow * 128 + (((4 * ks + q) + trow) & 15) * 8];
        sacc[mt][0] = MFMA16(kf, qf[0][ks], sacc[mt][0]);
        sacc[mt][1] = MFMA16(kf, qf[1][ks], sacc[mt][1]);
      }
    }

    // ---- V transpose via MFMA identity: Vt[d][t], wave w does d in [32w,32w+32)
#pragma unroll
    for (int mtv = 0; mtv < 4; ++mtv) {
      int trow = 16 * mtv + n;
      bf16x8 vfr = *(const bf16x8*)&sQ[8192 + trow * 128 + (((4 * w + q) + trow) & 15) * 8];
      f32x4 z = {0.f, 0.f, 0.f, 0.f};
      f32x4 d0 = MFMA16(vfr, idE, z);
      f32x4 d1 = MFMA16(vfr, idO, z);
      int G = 2 * mtv + (q >> 1), off = 4 * (q & 1);
      int dp0 = 32 * w + n, dp1 = dp0 + 16;
      uint2 u0 = {pk2(d0[0], d0[1]), pk2(d0[2], d0[3])};
      uint2 u1 = {pk2(d1[0], d1[1]), pk2(d1[2], d1[3])};
      *(uint2*)&sVt[dp0 * 64 + ((G + dp0) & 7) * 8 + off] = u0;
      *(uint2*)&sVt[dp1 * 64 + ((G + dp1) & 7) * 8 + off] = u1;
    }

    // ---- online softmax (in-register, rows r = 32w+16e+n) + write P
    float al[2];
#pragma unroll
    for (int e = 0; e < 2; ++e) {
      float sv[4][4];
      float mx = -INFINITY;
#pragma unroll
      for (int mt = 0; mt < 4; ++mt)
#pragma unroll
        for (int rg = 0; rg < 4; ++rg) {
          float v = sacc[mt][e][rg] + mv[mt][rg];
          sv[mt][rg] = v;
          mx = fmaxf(mx, v);
        }
      mx = fmaxf(mx, __shfl_xor(mx, 16));
      mx = fmaxf(mx, __shfl_xor(mx, 32));
      float mn = fmaxf(m_old[e], mx);
      al[e] = __expf(m_old[e] - mn);
      float ts = 0.f;
      int r = 32 * w + 16 * e + n;
#pragma unroll
      for (int mt = 0; mt < 4; ++mt) {
        float p0 = __expf(sv[mt][0] - mn), p1 = __expf(sv[mt][1] - mn);
        float p2 = __expf(sv[mt][2] - mn), p3 = __expf(sv[mt][3] - mn);
        ts += (p0 + p1) + (p2 + p3);
        uint2 up = {pk2(p0, p1), pk2(p2, p3)};
        int G = 2 * mt + (q >> 1), off = 4 * (q & 1);
        *(uint2*)&sP[r * 64 + ((G + r) & 7) * 8 + off] = up;
      }
      ts += __shfl_xor(ts, 16);
      ts += __shfl_xor(ts, 32);
      l_old[e] = l_old[e] * al[e] + ts;
      m_old[e] = mn;
    }
    __syncthreads();  // B

    // ---- O rescale (alpha via in-wave shuffle) + PV
#pragma unroll
    for (int e = 0; e < 2; ++e) {
      float an[4];
#pragma unroll
      for (int rg = 0; rg < 4; ++rg) an[rg] = __shfl(al[e], 4 * q + rg);
#pragma unroll
      for (int nt = 0; nt < 8; ++nt)
#pragma unroll
        for (int rg = 0; rg < 4; ++rg) oacc[e][nt][rg] *= an[rg];
    }
    bf16x8 Pf[2][2];
#pragma unroll
    for (int e = 0; e < 2; ++e) {
      int r = 32 * w + 16 * e + n;
#pragma unroll
      for (int ks = 0; ks < 2; ++ks)
        Pf[e][ks] = *(const bf16x8*)&sP[r * 64 + (((4 * ks + q) + r) & 7) * 8];
    }
#pragma unroll
    for (int nt = 0; nt < 8; ++nt) {
      int d = 16 * nt + n;
#pragma unroll
      for (int ks = 0; ks < 2; ++ks) {
        bf16x8 vf = *(const bf16x8*)&sVt[d * 64 + (((4 * ks + q) + d) & 7) * 8];
        oacc[0][nt] = MFMA16(Pf[0][ks], vf, oacc[0][nt]);
        oacc[1][nt] = MFMA16(Pf[1][ks], vf, oacc[1][nt]);
      }
    }
    __syncthreads();  // next staging may rewrite sQ; sP/sVt rewritten after A
  }

  // ---- epilogue: O^T bf16 -> sQ (rotated) -> coalesced global partials
#pragma unroll
  for (int e = 0; e < 2; ++e)
#pragma unroll
    for (int nt = 0; nt < 8; ++nt) {
      int d = 16 * nt + n;
      int r0 = 32 * w + 16 * e + 4 * q;
      int G = r0 >> 3, off = 4 * (q & 1);
      uint2 u = {pk2(oacc[e][nt][0], oacc[e][nt][1]),
                 pk2(oacc[e][nt][2], oacc[e][nt][3])};
      *(uint2*)&sQ[d * 128 + ((G + d) & 15) * 8 + off] = u;
    }
  if (q == 0) {
#pragma unroll
    for (int e = 0; e < 2; ++e) {
      int r = 32 * w + 16 * e + n;
      Mpart[(size_t)bid * 128 + r] = m_old[e];
      Lpart[(size_t)bid * 128 + r] = l_old[e];
    }
  }
  __syncthreads();
  for (int i = tid; i < 2048; i += 256) {
    int d = i >> 4, g = i & 15;
    uint4 v = *(const uint4*)&sQ[d * 128 + ((g + d) & 15) * 8];
    *(uint4*)(Opart + (size_t)bid * 16384 + d * 128 + g * 8) = v;
  }
}

// ---------------------------------------------------------------------------
// Combine 32 chunk partials -> A2t bf16 [j=b*16+s][c=h*128+d]
// grid (16 bk, 16 dgrp) x 256; 4 interleaved accumulators for load ILP.
// ---------------------------------------------------------------------------
__global__ __launch_bounds__(256) void combine(const u16* __restrict__ Opart,
                                               const float* __restrict__ Mp,
                                               const float* __restrict__ Lp,
                                               u16* __restrict__ A2t) {
  __shared__ float wgt[32 * 128];  // 16 KB
  const int tid = threadIdx.x;
  const int bk = blockIdx.x, dgrp = blockIdx.y;
  if (tid < 128) {
    int r = tid;
    float mc[32], M = -INFINITY;
#pragma unroll
    for (int c = 0; c < 32; ++c) {
      mc[c] = Mp[(size_t)(bk * 32 + c) * 128 + r];
      M = fmaxf(M, mc[c]);
    }
    float L = 0.f, wv[32];
#pragma unroll
    for (int c = 0; c < 32; ++c) {
      wv[c] = __expf(mc[c] - M);
      L += wv[c] * Lp[(size_t)(bk * 32 + c) * 128 + r];
    }
    float inv = 1.0f / L;
#pragma unroll
    for (int c = 0; c < 32; ++c) wgt[c * 128 + r] = wv[c] * inv;
  }
  __syncthreads();
  int r = tid & 127, dd = tid >> 7;
  int b = bk >> 1, kvh = bk & 1;
  int h = kvh * 8 + (r >> 4), s = r & 15;
  size_t arow = (size_t)(b * 16 + s) * 2048 + h * 128;
  float o[4] = {0.f, 0.f, 0.f, 0.f};
#pragma unroll
  for (int c = 0; c < 32; ++c) {
    float wv = wgt[c * 128 + r];
    size_t base = ((size_t)(bk * 32 + c) * 128) * 128 + r;
#pragma unroll
    for (int di = 0; di < 4; ++di) {
      int d = dgrp * 8 + dd + 2 * di;
      o[di] += wv * bf2f(Opart[base + (size_t)d * 128]);
    }
  }
#pragma unroll
  for (int di = 0; di < 4; ++di) {
    int d = dgrp * 8 + dd + 2 * di;
    A2t[arow + d] = f2bf(o[di]);
  }
}

// ---------------------------------------------------------------------------
extern "C" void kernel_launch(void* const* d_in, const int* in_sizes, int n_in,
                              void* d_out, int out_size, void* d_ws, size_t ws_size,
                              hipStream_t stream) {
  const float* x    = (const float*)d_in[0];
  const float* cosb = (const float*)d_in[1];
  const float* sinb = (const float*)d_in[2];
  const float* kc   = (const float*)d_in[3];
  const float* vc   = (const float*)d_in[4];
  const int*   posp = (const int*)d_in[5];
  const float* mask = (const float*)d_in[6];
  const float* wq   = (const float*)d_in[7];
  const float* wk   = (const float*)d_in[8];
  const float* wv   = (const float*)d_in[9];
  const float* wo   = (const float*)d_in[10];
  const float* qw   = (const float*)d_in[11];
  const float* kw   = (const float*)d_in[12];

  float* out  = (float*)d_out;
  float* outk = out + 262144;
  float* outv = outk + 16777216;

  // Workspace: region A (4,194,304 f32 = 16 MB) is time-shared:
  //   [gemm<0> partials 8x327680=2,621,440] -> dead before attn
  //   [attn Opart 8,388,608 u16 = 4,194,304 f32] -> dead before gemm<1>
  //   [gemm<1> partials 8x262144=2,097,152] -> reduced into out
  float* ws     = (float*)d_ws;
  float* ws_A   = ws;                         // 4,194,304 f32
  float* ws_knew = ws + 4194304;              // 32768
  float* ws_vnew = ws + 4227072;              // 32768
  u16*   ws_Qa   = (u16*)(ws + 4259840);      // 262144 u16
  u16*   ws_Xt   = (u16*)(ws + 4390912);      // 262144 u16
  u16*   ws_A2t  = (u16*)(ws + 4521984);      // 262144 u16
  float* ws_M    = ws + 4653056;              // 65536
  float* ws_L    = ws + 4718592;              // 65536
  // total = 4,784,128 floats = 19.14 MB

  float* ws_qkvp = ws_A;        // gemm<0> partials
  u16*   ws_O    = (u16*)ws_A;  // attn partials
  float* ws_op   = ws_A;        // gemm<1> partials

  transpose_x<<<256, 256, 0, stream>>>(x, ws_Xt);
  gemm16<0><<<dim3(160, 8), 256, 0, stream>>>(wq, wk, wv, ws_Xt, ws_qkvp);
  norm_rot<<<640, 256, 0, stream>>>(ws_qkvp, cosb, sinb, qw, kw,
                                    ws_Qa, ws_knew, ws_vnew);
  attn<<<512, 256, 0, stream>>>(ws_Qa, kc, vc, ws_knew, ws_vnew, posp, mask,
                                outk, outv, ws_O, ws_M, ws_L);
  combine<<<dim3(16, 16), 256, 0, stream>>>(ws_O, ws_M, ws_L, ws_A2t);
  gemm16<1><<<dim3(128, 8), 256, 0, stream>>>(wo, wo, wo, ws_A2t, ws_op);
  reduce_out<<<256, 256, 0, stream>>>(ws_op, out);
}